// Round 5
// baseline (381.449 us; speedup 1.0000x reference)
//
#include <hip/hip_runtime.h>
#include <cstdint>
#include <cstddef>

// ---------------- workspace layout (bytes) ----------------
// Wp   : packed gate-interleaved weight, bf16, 768x1024 (4 cb x 32 kb tiles, 192x32) = 1,572,864
// Fp   : packed fco_w, bf16, 256x256 (2 nb x 8 kb tiles, 128x32)                     =   131,072
// bp   : permuted bias (c = h*3+g), f32, 768
// hvp  : packed hidden vector, bf16, 32768x256 (256 mb x 8 kb tiles, 128x32)
#define WS_WP   0
#define WS_FCO  1572864
#define WS_BP   1703936
#define WS_HVP  1707008

typedef __attribute__((ext_vector_type(8))) __bf16 bf16x8;
typedef __attribute__((ext_vector_type(4))) float floatx4;

__device__ __forceinline__ unsigned short f2bf(float f) {
  unsigned int u = __builtin_bit_cast(unsigned int, f);
  u += 0x7fffu + ((u >> 16) & 1u);   // RNE
  return (unsigned short)(u >> 16);
}

__device__ __forceinline__ float sigmf(float z) {
  return __builtin_amdgcn_rcpf(1.f + __expf(-z));
}
__device__ __forceinline__ float tanh_(float z) {
  return 1.f - 2.f * __builtin_amdgcn_rcpf(1.f + __expf(2.f * z));
}

__device__ __forceinline__ void gld16(const void* g, void* l) {
  __builtin_amdgcn_global_load_lds(
      (const __attribute__((address_space(1))) unsigned int*)g,
      (__attribute__((address_space(3))) unsigned int*)l, 16, 0, 0);
}

// ---------------- merged pack kernel ----------------
// blocks 0..383: quaternion weight pack, 192-col tiles (cb=c/192, kb=f/32),
//   slot idx16 = nl*4 + (q ^ ((nl>>1)&3)). Lane = h (coalesced reads).
// blocks 384..415: fco_w pack, 128-col tiles. Lane = n (coalesced).
__global__ __launch_bounds__(256) void pack_k(
    const float* __restrict__ wr, const float* __restrict__ wi,
    const float* __restrict__ wj, const float* __restrict__ wk,
    const float* __restrict__ bx, const float* __restrict__ fw,
    unsigned short* __restrict__ Wp, unsigned short* __restrict__ Fp,
    float* __restrict__ bp) {
  int t = threadIdx.x;
  if (blockIdx.x < 384) {
    int gpp = blockIdx.x >> 7;        // 0..2 -> gates {input,output,cell}
    int oct = blockIdx.x & 127;       // f-octet
    int gp = gpp + 1;                 // skip dead forget gate
    int h = t;                        // 0..255, lane-contiguous
    int hb = h >> 6, hr = h & 63;     // hb wave-uniform
    int f0 = oct << 3;
    int fb = f0 >> 8, fr0 = f0 & 255;
    const int   comp_t[4][4] = {{0,1,2,3},{1,0,3,2},{2,3,0,1},{3,2,1,0}};
    const float sign_t[4][4] = {{1.f,-1.f,-1.f,-1.f},{1.f,1.f,-1.f,1.f},
                                {1.f,1.f,1.f,-1.f},{1.f,-1.f,1.f,1.f}};
    const float* srcs[4] = {wr, wi, wj, wk};
    const float* s = srcs[comp_t[hb][fb]] + ((size_t)((gp << 8) + fr0)) * 64 + hr;
    float sg = sign_t[hb][fb];
    unsigned short v[8];
#pragma unroll
    for (int j = 0; j < 8; ++j) v[j] = f2bf(sg * s[(size_t)j * 64]);
    int c = h * 3 + gpp;
    int cb = c / 192, nl = c % 192;
    int kb = oct >> 2, q = oct & 3;
    int idx16 = (nl << 2) + (q ^ ((nl >> 1) & 3));
    uint4 val = make_uint4(
        (unsigned)v[0] | ((unsigned)v[1] << 16), (unsigned)v[2] | ((unsigned)v[3] << 16),
        (unsigned)v[4] | ((unsigned)v[5] << 16), (unsigned)v[6] | ((unsigned)v[7] << 16));
    *(uint4*)(Wp + (size_t)(cb * 32 + kb) * 6144 + idx16 * 8) = val;
    if (oct == 0) bp[c] = bx[(gp << 8) + h];
  } else {
    int oct = blockIdx.x - 384;       // k-octet 0..31
    int n = t;
    int k0 = oct << 3;
    unsigned short v[8];
#pragma unroll
    for (int j = 0; j < 8; ++j) v[j] = f2bf(fw[(size_t)(k0 + j) * 256 + n]);
    int nb = n >> 7, nl = n & 127, kb = oct >> 2, q = oct & 3;
    int idx16 = (nl << 2) + (q ^ ((nl >> 1) & 3));
    uint4 val = make_uint4(
        (unsigned)v[0] | ((unsigned)v[1] << 16), (unsigned)v[2] | ((unsigned)v[3] << 16),
        (unsigned)v[4] | ((unsigned)v[5] << 16), (unsigned)v[6] | ((unsigned)v[7] << 16));
    *(uint4*)(Fp + (size_t)((nb << 3) + kb) * 4096 + idx16 * 8) = val;
  }
}

// ---------------- GEMM1 + fused LSTM gates: barrier-free direct-register K-loop ----------------
// Tile 128x192, 4 waves of 64x96, acc[4][6]. A fp32 direct global->VGPR (cvt in
// register), B direct from packed Wp (contiguous 1KB/instr). Register double-
// buffer prefetches kt+1 during kt's MFMAs. No LDS, no barriers in the K-loop.
__global__ __launch_bounds__(256, 2) void gemm1_k(
    const float* __restrict__ x, const unsigned short* __restrict__ Wp,
    const float* __restrict__ bp, unsigned short* __restrict__ hvp) {
  __shared__ float zep[64 * 201];               // epilogue only: 51456 B

  const int t = threadIdx.x;
  const int lane = t & 63, wid = t >> 6;
  const int wm = wid >> 1, wn = wid & 1;
  const int lrow = lane & 15, q = lane >> 4;
  const int cby = blockIdx.x;                   // 0..3 (192 interleaved cols = 64 h)
  const int rowt = blockIdx.y;                  // 0..255
  const int row0 = rowt * 128;

  const float* xw = x + (size_t)(row0 + wm * 64 + lrow) * 1024 + q * 8;
  const unsigned short* wpb = Wp + (size_t)cby * 32 * 6144;

  int boff[6];
#pragma unroll
  for (int nt = 0; nt < 6; ++nt) {
    int n = wn * 96 + nt * 16 + lrow;
    boff[nt] = (n * 4 + (q ^ ((n >> 1) & 3))) * 8;
  }

  float4 a[2][4][2];
  bf16x8 b[2][6];
  floatx4 acc[4][6];
#pragma unroll
  for (int i = 0; i < 4; ++i)
#pragma unroll
    for (int j = 0; j < 6; ++j) acc[i][j] = (floatx4){0.f, 0.f, 0.f, 0.f};

  // prologue: kt = 0
#pragma unroll
  for (int mt = 0; mt < 4; ++mt) {
    const float* p = xw + (size_t)mt * 16 * 1024;
    a[0][mt][0] = *(const float4*)(p);
    a[0][mt][1] = *(const float4*)(p + 4);
  }
#pragma unroll
  for (int nt = 0; nt < 6; ++nt)
    b[0][nt] = *(const bf16x8*)(const void*)(wpb + boff[nt]);

#pragma unroll
  for (int kt = 0; kt < 32; ++kt) {
    const int cur = kt & 1, nxt = cur ^ 1;
    if (kt < 31) {
      const float* xk = xw + (kt + 1) * 32;
      const unsigned short* bt = wpb + (size_t)(kt + 1) * 6144;
#pragma unroll
      for (int mt = 0; mt < 4; ++mt) {
        const float* p = xk + (size_t)mt * 16 * 1024;
        a[nxt][mt][0] = *(const float4*)(p);
        a[nxt][mt][1] = *(const float4*)(p + 4);
      }
#pragma unroll
      for (int nt = 0; nt < 6; ++nt)
        b[nxt][nt] = *(const bf16x8*)(const void*)(bt + boff[nt]);
    }
#pragma unroll
    for (int mt = 0; mt < 4; ++mt) {
      const float4 a0 = a[cur][mt][0], a1 = a[cur][mt][1];
      bf16x8 av;
      av[0] = (__bf16)a0.x; av[1] = (__bf16)a0.y; av[2] = (__bf16)a0.z; av[3] = (__bf16)a0.w;
      av[4] = (__bf16)a1.x; av[5] = (__bf16)a1.y; av[6] = (__bf16)a1.z; av[7] = (__bf16)a1.w;
#pragma unroll
      for (int nt = 0; nt < 6; ++nt)
        acc[mt][nt] = __builtin_amdgcn_mfma_f32_16x16x32_bf16(av, b[cur][nt], acc[mt][nt], 0, 0, 0);
    }
  }

  // Epilogue: 2 passes of 64 rows via LDS (pitch 201 f32), fused gates,
  // hv stored in gemm2's packed-swizzled tile layout.
  const float* bp0 = bp + cby * 192;
  const int er = t >> 2, oc = t & 3;
#pragma unroll
  for (int pass = 0; pass < 2; ++pass) {
    if (wm == pass) {
#pragma unroll
      for (int mt = 0; mt < 4; ++mt)
#pragma unroll
        for (int nt = 0; nt < 6; ++nt)
#pragma unroll
          for (int r = 0; r < 4; ++r)
            zep[(mt * 16 + q * 4 + r) * 201 + wn * 96 + nt * 16 + lrow] = acc[mt][nt][r];
    }
    __syncthreads();
    int ml = pass * 64 + er;
#pragma unroll
    for (int half = 0; half < 2; ++half) {
      int oo = oc + half * 4;                   // h-octet 0..7 within the 64-h block
      unsigned short v[8];
#pragma unroll
      for (int j = 0; j < 8; ++j) {
        int hl = oo * 8 + j;                    // 0..63 local h
        float zi = zep[er * 201 + hl * 3 + 0] + bp0[hl * 3 + 0];
        float zo = zep[er * 201 + hl * 3 + 1] + bp0[hl * 3 + 1];
        float zc = zep[er * 201 + hl * 3 + 2] + bp0[hl * 3 + 2];
        float it = sigmf(zi);
        float ot = sigmf(zo);
        float cc = it * tanh_(zc);
        v[j] = f2bf(ot * tanh_(cc));
      }
      int ktile = cby * 2 + (oo >> 2), qq = oo & 3;
      int idx16 = (ml << 2) + (qq ^ ((ml >> 1) & 3));
      uint4 val = make_uint4(
          (unsigned)v[0] | ((unsigned)v[1] << 16), (unsigned)v[2] | ((unsigned)v[3] << 16),
          (unsigned)v[4] | ((unsigned)v[5] << 16), (unsigned)v[6] | ((unsigned)v[7] << 16));
      *(uint4*)(hvp + (size_t)(rowt * 8 + ktile) * 4096 + idx16 * 8) = val;
    }
    __syncthreads();
  }
}

// ---------------- GEMM2: out = hv @ fco_w + fco_b (fp32 output) ----------------
// B-half (256x128) resident in LDS (loaded once); A fragments direct global->VGPR
// from packed hvp. No barriers in the K-loop.
__global__ __launch_bounds__(256, 4) void gemm2_k(
    const unsigned short* __restrict__ hvp, const unsigned short* __restrict__ Fp,
    const float* __restrict__ fcob, float* __restrict__ out) {
  __shared__ unsigned short sB[32768];          // 64 KB: 8 k-tiles of 128x32
  const int t = threadIdx.x;
  const int lane = t & 63, wid = t >> 6;
  const int wm = wid >> 1, wn = wid & 1;
  const int lrow = lane & 15, q = lane >> 4;
  const int mb = blockIdx.x, nb = blockIdx.y;

  const unsigned short* fpb = Fp + (size_t)nb * 32768;
#pragma unroll
  for (int i = 0; i < 16; ++i) gld16(fpb + (t + i * 256) * 8, sB + (t + i * 256) * 8);

  floatx4 acc[4][4];
#pragma unroll
  for (int i = 0; i < 4; ++i)
#pragma unroll
    for (int j = 0; j < 4; ++j) acc[i][j] = (floatx4){0.f, 0.f, 0.f, 0.f};
  __syncthreads();

#pragma unroll
  for (int kt = 0; kt < 8; ++kt) {
    const unsigned short* at_ = hvp + (size_t)(mb * 8 + kt) * 4096;
    bf16x8 af[4], bf[4];
#pragma unroll
    for (int mt = 0; mt < 4; ++mt) {
      int m = wm * 64 + mt * 16 + lrow;
      int o = (m << 2) + (q ^ ((m >> 1) & 3));
      af[mt] = *(const bf16x8*)(const void*)(at_ + o * 8);    // global, coalesced
    }
#pragma unroll
    for (int nt = 0; nt < 4; ++nt) {
      int n = wn * 64 + nt * 16 + lrow;
      int o = (n << 2) + (q ^ ((n >> 1) & 3));
      bf[nt] = *(const bf16x8*)(const void*)(sB + kt * 4096 + o * 8);
    }
#pragma unroll
    for (int mt = 0; mt < 4; ++mt)
#pragma unroll
      for (int nt = 0; nt < 4; ++nt)
        acc[mt][nt] = __builtin_amdgcn_mfma_f32_16x16x32_bf16(af[mt], bf[nt], acc[mt][nt], 0, 0, 0);
  }
#pragma unroll
  for (int nt = 0; nt < 4; ++nt) {
    int colg = nb * 128 + wn * 64 + nt * 16 + lrow;
    float bias = fcob[colg];
#pragma unroll
    for (int mt = 0; mt < 4; ++mt) {
      int rowg = mb * 128 + wm * 64 + mt * 16 + q * 4;
#pragma unroll
      for (int r = 0; r < 4; ++r)
        out[(size_t)(rowg + r) * 256 + colg] = acc[mt][nt][r] + bias;
    }
  }
}

extern "C" void kernel_launch(void* const* d_in, const int* in_sizes, int n_in,
                              void* d_out, int out_size, void* d_ws, size_t ws_size,
                              hipStream_t stream) {
  const float* x  = (const float*)d_in[0];
  const float* wr = (const float*)d_in[1];
  const float* wi = (const float*)d_in[2];
  const float* wj = (const float*)d_in[3];
  const float* wk = (const float*)d_in[4];
  const float* bx = (const float*)d_in[5];
  // d_in[6..9] = uh_* are dead (h0 == 0)
  const float* fw = (const float*)d_in[10];
  const float* fb = (const float*)d_in[11];
  char* ws = (char*)d_ws;
  unsigned short* Wp  = (unsigned short*)(ws + WS_WP);
  unsigned short* Fp  = (unsigned short*)(ws + WS_FCO);
  float*          bp  = (float*)(ws + WS_BP);
  unsigned short* hvp = (unsigned short*)(ws + WS_HVP);
  float*          out = (float*)d_out;

  hipLaunchKernelGGL(pack_k,  dim3(416),    dim3(256), 0, stream, wr, wi, wj, wk, bx, fw, Wp, Fp, bp);
  hipLaunchKernelGGL(gemm1_k, dim3(4, 256), dim3(256), 0, stream, x, Wp, bp, hvp);
  hipLaunchKernelGGL(gemm2_k, dim3(256, 2), dim3(256), 0, stream, hvp, Fp, fb, out);
}

// Round 6
// 289.289 us; speedup vs baseline: 1.3186x; 1.3186x over previous
//
#include <hip/hip_runtime.h>
#include <cstdint>
#include <cstddef>

// ---------------- workspace layout (bytes) ----------------
// Wp   : packed gate-interleaved weight, bf16, 768x1024 (4 cb x 32 kb tiles, 192x32) = 1,572,864
// Fp   : packed fco_w, bf16, 256x256 (2 nb x 8 kb tiles, 128x32)                     =   131,072
// bp   : permuted bias (c = h*3+g), f32, 768
// hvp  : packed hidden vector, bf16, 32768x256 (256 mb x 8 kb tiles, 128x32)
#define WS_WP   0
#define WS_FCO  1572864
#define WS_BP   1703936
#define WS_HVP  1707008

typedef __attribute__((ext_vector_type(8))) __bf16 bf16x8;
typedef __attribute__((ext_vector_type(4))) float floatx4;

__device__ __forceinline__ unsigned short f2bf(float f) {
  unsigned int u = __builtin_bit_cast(unsigned int, f);
  u += 0x7fffu + ((u >> 16) & 1u);   // RNE
  return (unsigned short)(u >> 16);
}

__device__ __forceinline__ float sigmf(float z) {
  return __builtin_amdgcn_rcpf(1.f + __expf(-z));
}
__device__ __forceinline__ float tanh_(float z) {
  return 1.f - 2.f * __builtin_amdgcn_rcpf(1.f + __expf(2.f * z));
}

__device__ __forceinline__ void gld16(const void* g, void* l) {
  __builtin_amdgcn_global_load_lds(
      (const __attribute__((address_space(1))) unsigned int*)g,
      (__attribute__((address_space(3))) unsigned int*)l, 16, 0, 0);
}

// ---------------- merged pack kernel ----------------
// blocks 0..383: quaternion weight pack, 192-col tiles (cb=c/192, kb=f/32),
//   slot idx16 = nl*4 + (q ^ ((nl>>1)&3)). Lane = h (coalesced reads).
// blocks 384..415: fco_w pack, 128-col tiles. Lane = n (coalesced).
__global__ __launch_bounds__(256) void pack_k(
    const float* __restrict__ wr, const float* __restrict__ wi,
    const float* __restrict__ wj, const float* __restrict__ wk,
    const float* __restrict__ bx, const float* __restrict__ fw,
    unsigned short* __restrict__ Wp, unsigned short* __restrict__ Fp,
    float* __restrict__ bp) {
  int t = threadIdx.x;
  if (blockIdx.x < 384) {
    int gpp = blockIdx.x >> 7;        // 0..2 -> gates {input,output,cell}
    int oct = blockIdx.x & 127;       // f-octet
    int gp = gpp + 1;                 // skip dead forget gate
    int h = t;                        // 0..255, lane-contiguous
    int hb = h >> 6, hr = h & 63;     // hb wave-uniform
    int f0 = oct << 3;
    int fb = f0 >> 8, fr0 = f0 & 255;
    const int   comp_t[4][4] = {{0,1,2,3},{1,0,3,2},{2,3,0,1},{3,2,1,0}};
    const float sign_t[4][4] = {{1.f,-1.f,-1.f,-1.f},{1.f,1.f,-1.f,1.f},
                                {1.f,1.f,1.f,-1.f},{1.f,-1.f,1.f,1.f}};
    const float* srcs[4] = {wr, wi, wj, wk};
    const float* s = srcs[comp_t[hb][fb]] + ((size_t)((gp << 8) + fr0)) * 64 + hr;
    float sg = sign_t[hb][fb];
    unsigned short v[8];
#pragma unroll
    for (int j = 0; j < 8; ++j) v[j] = f2bf(sg * s[(size_t)j * 64]);
    int c = h * 3 + gpp;
    int cb = c / 192, nl = c % 192;
    int kb = oct >> 2, q = oct & 3;
    int idx16 = (nl << 2) + (q ^ ((nl >> 1) & 3));
    uint4 val = make_uint4(
        (unsigned)v[0] | ((unsigned)v[1] << 16), (unsigned)v[2] | ((unsigned)v[3] << 16),
        (unsigned)v[4] | ((unsigned)v[5] << 16), (unsigned)v[6] | ((unsigned)v[7] << 16));
    *(uint4*)(Wp + (size_t)(cb * 32 + kb) * 6144 + idx16 * 8) = val;
    if (oct == 0) bp[c] = bx[(gp << 8) + h];
  } else {
    int oct = blockIdx.x - 384;       // k-octet 0..31
    int n = t;
    int k0 = oct << 3;
    unsigned short v[8];
#pragma unroll
    for (int j = 0; j < 8; ++j) v[j] = f2bf(fw[(size_t)(k0 + j) * 256 + n]);
    int nb = n >> 7, nl = n & 127, kb = oct >> 2, q = oct & 3;
    int idx16 = (nl << 2) + (q ^ ((nl >> 1) & 3));
    uint4 val = make_uint4(
        (unsigned)v[0] | ((unsigned)v[1] << 16), (unsigned)v[2] | ((unsigned)v[3] << 16),
        (unsigned)v[4] | ((unsigned)v[5] << 16), (unsigned)v[6] | ((unsigned)v[7] << 16));
    *(uint4*)(Fp + (size_t)((nb << 3) + kb) * 4096 + idx16 * 8) = val;
  }
}

// ---------------- GEMM1 + fused LSTM gates: double-buffered LDS K-loop ----------------
// Tile 128x192, 4 waves of 64x96, BK=32, acc[4][6]. A fp32 via global_load_lds with
// XOR-quad swizzle (cvt to bf16 after ds_read); B from pre-swizzled Wp. Two 28-KB
// staging buffers: loads for step k+1 issue right after the barrier, so the next
// barrier's vmcnt(0) drain lands after the compute phase has covered the latency.
__global__ __launch_bounds__(256, 2) void gemm1_k(
    const float* __restrict__ x, const unsigned short* __restrict__ Wp,
    const float* __restrict__ bp, unsigned short* __restrict__ hvp) {
  __shared__ char smem[57344];                  // 2 x (A fp32 16K + B bf16 12K); epi 64x201 f32
  float* zep = (float*)smem;

  const int t = threadIdx.x;
  const int lane = t & 63, wid = t >> 6;
  const int wm = wid >> 1, wn = wid & 1;
  const int lrow = lane & 15, q = lane >> 4;
  const int rowt = blockIdx.x;                  // 0..255 (fast dim: W stays L2-hot)
  const int cby = blockIdx.y;                   // 0..3, 192 interleaved cols (64 h)
  const int row0 = rowt * 128;
  const float* xbase = x + (size_t)row0 * 1024;
  const unsigned short* wpb = Wp + (size_t)cby * 32 * 6144;

  floatx4 acc[4][6];
#pragma unroll
  for (int i = 0; i < 4; ++i)
#pragma unroll
    for (int j = 0; j < 6; ++j) acc[i][j] = (floatx4){0.f, 0.f, 0.f, 0.f};

  // stage(buf, kt): B 768 slots (3 instr/thread), A 1024 slots (4 instr/thread)
#define STAGE(buf, kt)                                                        \
  {                                                                           \
    char* base_ = smem + (buf) * 28672;                                       \
    float* sAf_ = (float*)base_;                                              \
    unsigned short* sBs_ = (unsigned short*)(base_ + 16384);                  \
    const unsigned short* bt_ = wpb + (size_t)(kt) * 6144;                    \
    const int k0_ = (kt) * 32;                                                \
    _Pragma("unroll")                                                         \
    for (int i_ = 0; i_ < 3; ++i_) {                                          \
      int s_ = t + i_ * 256;                                                  \
      gld16(bt_ + s_ * 8, sBs_ + s_ * 8);                                     \
    }                                                                         \
    _Pragma("unroll")                                                         \
    for (int i_ = 0; i_ < 4; ++i_) {                                          \
      int s_ = t + i_ * 256;                                                  \
      int m_ = s_ >> 3, j_ = s_ & 7, jj_ = j_ ^ (m_ & 7);                     \
      gld16(xbase + (size_t)m_ * 1024 + k0_ + jj_ * 4, sAf_ + s_ * 4);        \
    }                                                                         \
  }

  STAGE(0, 0)
  for (int kt = 0; kt < 32; ++kt) {
    __syncthreads();                            // drains stage(kt); prior reads done
    if (kt < 31) STAGE((kt + 1) & 1, kt + 1)    // prefetch into the other buffer
    char* base = smem + (kt & 1) * 28672;
    float* sAf = (float*)base;
    unsigned short* sBs = (unsigned short*)(base + 16384);
    bf16x8 af[4], bf[6];
#pragma unroll
    for (int mt = 0; mt < 4; ++mt) {
      int m = wm * 64 + mt * 16 + lrow;
      const float4 a0 = *(const float4*)(sAf + (m * 8 + ((2 * q) ^ (m & 7))) * 4);
      const float4 a1 = *(const float4*)(sAf + (m * 8 + ((2 * q + 1) ^ (m & 7))) * 4);
      bf16x8 v;
      v[0] = (__bf16)a0.x; v[1] = (__bf16)a0.y; v[2] = (__bf16)a0.z; v[3] = (__bf16)a0.w;
      v[4] = (__bf16)a1.x; v[5] = (__bf16)a1.y; v[6] = (__bf16)a1.z; v[7] = (__bf16)a1.w;
      af[mt] = v;
    }
#pragma unroll
    for (int nt = 0; nt < 6; ++nt) {
      int n = wn * 96 + nt * 16 + lrow;
      int off16 = (n << 2) + (q ^ ((n >> 1) & 3));
      bf[nt] = *(const bf16x8*)(const void*)(sBs + off16 * 8);
    }
#pragma unroll
    for (int mt = 0; mt < 4; ++mt)
#pragma unroll
      for (int nt = 0; nt < 6; ++nt)
        acc[mt][nt] = __builtin_amdgcn_mfma_f32_16x16x32_bf16(af[mt], bf[nt], acc[mt][nt], 0, 0, 0);
  }
#undef STAGE
  __syncthreads();                              // all K-loop LDS reads done before zep reuse

  // Epilogue: 2 passes of 64 rows via LDS (pitch 201 f32), fused gates,
  // hv stored in gemm2's packed-swizzled tile layout.
  const float* bp0 = bp + cby * 192;
  const int er = t >> 2, oc = t & 3;
#pragma unroll
  for (int pass = 0; pass < 2; ++pass) {
    if (wm == pass) {
#pragma unroll
      for (int mt = 0; mt < 4; ++mt)
#pragma unroll
        for (int nt = 0; nt < 6; ++nt)
#pragma unroll
          for (int r = 0; r < 4; ++r)
            zep[(mt * 16 + q * 4 + r) * 201 + wn * 96 + nt * 16 + lrow] = acc[mt][nt][r];
    }
    __syncthreads();
    int ml = pass * 64 + er;
#pragma unroll
    for (int half = 0; half < 2; ++half) {
      int oo = oc + half * 4;                   // h-octet 0..7 within the 64-h block
      unsigned short v[8];
#pragma unroll
      for (int j = 0; j < 8; ++j) {
        int hl = oo * 8 + j;                    // 0..63 local h
        float zi = zep[er * 201 + hl * 3 + 0] + bp0[hl * 3 + 0];
        float zo = zep[er * 201 + hl * 3 + 1] + bp0[hl * 3 + 1];
        float zc = zep[er * 201 + hl * 3 + 2] + bp0[hl * 3 + 2];
        float it = sigmf(zi);
        float ot = sigmf(zo);
        float cc = it * tanh_(zc);
        v[j] = f2bf(ot * tanh_(cc));
      }
      int ktile = cby * 2 + (oo >> 2), qq = oo & 3;
      int idx16 = (ml << 2) + (qq ^ ((ml >> 1) & 3));
      uint4 val = make_uint4(
          (unsigned)v[0] | ((unsigned)v[1] << 16), (unsigned)v[2] | ((unsigned)v[3] << 16),
          (unsigned)v[4] | ((unsigned)v[5] << 16), (unsigned)v[6] | ((unsigned)v[7] << 16));
      *(uint4*)(hvp + (size_t)(rowt * 8 + ktile) * 4096 + idx16 * 8) = val;
    }
    __syncthreads();
  }
}

// ---------------- GEMM2: out = hv @ fco_w + fco_b (fp32 output) ----------------
// B-half (256x128) resident in LDS (loaded once); A fragments direct global->VGPR
// from packed hvp (1KB-contiguous per instr). No barriers in the K-loop.
__global__ __launch_bounds__(256, 4) void gemm2_k(
    const unsigned short* __restrict__ hvp, const unsigned short* __restrict__ Fp,
    const float* __restrict__ fcob, float* __restrict__ out) {
  __shared__ unsigned short sB[32768];          // 64 KB: 8 k-tiles of 128x32
  const int t = threadIdx.x;
  const int lane = t & 63, wid = t >> 6;
  const int wm = wid >> 1, wn = wid & 1;
  const int lrow = lane & 15, q = lane >> 4;
  const int mb = blockIdx.x, nb = blockIdx.y;

  const unsigned short* fpb = Fp + (size_t)nb * 32768;
#pragma unroll
  for (int i = 0; i < 16; ++i) gld16(fpb + (t + i * 256) * 8, sB + (t + i * 256) * 8);

  floatx4 acc[4][4];
#pragma unroll
  for (int i = 0; i < 4; ++i)
#pragma unroll
    for (int j = 0; j < 4; ++j) acc[i][j] = (floatx4){0.f, 0.f, 0.f, 0.f};
  __syncthreads();

#pragma unroll
  for (int kt = 0; kt < 8; ++kt) {
    const unsigned short* at_ = hvp + (size_t)(mb * 8 + kt) * 4096;
    bf16x8 af[4], bf[4];
#pragma unroll
    for (int mt = 0; mt < 4; ++mt) {
      int m = wm * 64 + mt * 16 + lrow;
      int o = (m << 2) + (q ^ ((m >> 1) & 3));
      af[mt] = *(const bf16x8*)(const void*)(at_ + o * 8);    // global, coalesced
    }
#pragma unroll
    for (int nt = 0; nt < 4; ++nt) {
      int n = wn * 64 + nt * 16 + lrow;
      int o = (n << 2) + (q ^ ((n >> 1) & 3));
      bf[nt] = *(const bf16x8*)(const void*)(sB + kt * 4096 + o * 8);
    }
#pragma unroll
    for (int mt = 0; mt < 4; ++mt)
#pragma unroll
      for (int nt = 0; nt < 4; ++nt)
        acc[mt][nt] = __builtin_amdgcn_mfma_f32_16x16x32_bf16(af[mt], bf[nt], acc[mt][nt], 0, 0, 0);
  }
#pragma unroll
  for (int nt = 0; nt < 4; ++nt) {
    int colg = nb * 128 + wn * 64 + nt * 16 + lrow;
    float bias = fcob[colg];
#pragma unroll
    for (int mt = 0; mt < 4; ++mt) {
      int rowg = mb * 128 + wm * 64 + mt * 16 + q * 4;
#pragma unroll
      for (int r = 0; r < 4; ++r)
        out[(size_t)(rowg + r) * 256 + colg] = acc[mt][nt][r] + bias;
    }
  }
}

extern "C" void kernel_launch(void* const* d_in, const int* in_sizes, int n_in,
                              void* d_out, int out_size, void* d_ws, size_t ws_size,
                              hipStream_t stream) {
  const float* x  = (const float*)d_in[0];
  const float* wr = (const float*)d_in[1];
  const float* wi = (const float*)d_in[2];
  const float* wj = (const float*)d_in[3];
  const float* wk = (const float*)d_in[4];
  const float* bx = (const float*)d_in[5];
  // d_in[6..9] = uh_* are dead (h0 == 0)
  const float* fw = (const float*)d_in[10];
  const float* fb = (const float*)d_in[11];
  char* ws = (char*)d_ws;
  unsigned short* Wp  = (unsigned short*)(ws + WS_WP);
  unsigned short* Fp  = (unsigned short*)(ws + WS_FCO);
  float*          bp  = (float*)(ws + WS_BP);
  unsigned short* hvp = (unsigned short*)(ws + WS_HVP);
  float*          out = (float*)d_out;

  hipLaunchKernelGGL(pack_k,  dim3(416),    dim3(256), 0, stream, wr, wi, wj, wk, bx, fw, Wp, Fp, bp);
  hipLaunchKernelGGL(gemm1_k, dim3(256, 4), dim3(256), 0, stream, x, Wp, bp, hvp);
  hipLaunchKernelGGL(gemm2_k, dim3(256, 2), dim3(256), 0, stream, hvp, Fp, fb, out);
}